// Round 7
// baseline (226.908 us; speedup 1.0000x reference)
//
#include <hip/hip_runtime.h>
#include <math.h>

#define B_    4
#define S_    2048
#define BS_   8192       // B_*S_
#define DM_   1024
#define DS_   256
#define LB_   64
#define TOPK_ 8

typedef unsigned short u16;
typedef __bf16 bf16x8 __attribute__((ext_vector_type(8)));
typedef __bf16 bf16x4 __attribute__((ext_vector_type(4)));
typedef float  f32x4  __attribute__((ext_vector_type(4)));

static __device__ __forceinline__ u16 f2bf(float f) {
    union { float f; unsigned u; } a; a.f = f;
    unsigned u = a.u;
    unsigned r = u + 0x7FFFu + ((u >> 16) & 1u);   // RNE
    return (u16)(r >> 16);
}
static __device__ __forceinline__ float bf2f(u16 v) {
    union { unsigned u; float f; } a; a.u = ((unsigned)v) << 16; return a.f;
}
static __device__ __forceinline__ unsigned pack2(float a, float b) {
    return (unsigned)f2bf(a) | ((unsigned)f2bf(b) << 16);
}

// ---------------------------------------------------------------------------
// MFMA bf16 GEMM, BK=128: C = epi(A_bf16[M,K] @ Bt_bf16[N,K]^T + bias[N])
// MF = M-frags/wave (2 -> BM=64, 4 -> BM=128). BN=64. 256 thr = 4 waves (2x2).
// LDS rows 256B (16 granules), swizzle g^(row&15). 1-D grid, XCD-chunked.
// EPI: 0 -> C bf16 | 2 -> C bf16 = extra0_bf16 + val*extra1[m] | 3 -> C f32 =
// extra0_bf16 + val.
// ---------------------------------------------------------------------------
template<int MF, int EPI>
__global__ __launch_bounds__(256) void mm_k(
    const u16* __restrict__ A, const u16* __restrict__ Bt,
    const float* __restrict__ bias, void* __restrict__ Cv,
    int M, int K, int N, int gx,
    const void* __restrict__ extra0v, const float* __restrict__ extra1)
{
    constexpr int BM = MF * 32;
    __shared__ __align__(16) unsigned char smem[BM * 256 + 64 * 256];
    unsigned char* smA = smem;
    unsigned char* smB = smem + BM * 256;

    const int nb  = gridDim.x;
    const int per = nb >> 3;
    const int id  = blockIdx.x;
    const int nid = (id & 7) * per + (id >> 3);   // bijective XCD chunking
    const int bx  = nid % gx, by = nid / gx;

    const int tid  = threadIdx.x;
    const int lane = tid & 63, wid = tid >> 6;
    const int wm   = wid >> 1, wn = wid & 1;
    const int bm   = by * BM, bn = bx * 64;
    const int lr   = lane & 15, lc = lane >> 4;

    f32x4 acc[MF][2] = {};

    for (int k0 = 0; k0 < K; k0 += 128) {
        #pragma unroll
        for (int i = 0; i < MF * 2; ++i) {
            int e = tid + i * 256;
            int row = e >> 4, g = e & 15;
            uint4 v = *reinterpret_cast<const uint4*>(
                A + (size_t)(bm + row) * K + k0 + g * 8);
            *reinterpret_cast<uint4*>(smA + row * 256 + ((g ^ (row & 15)) * 16)) = v;
        }
        #pragma unroll
        for (int i = 0; i < 4; ++i) {
            int e = tid + i * 256;
            int row = e >> 4, g = e & 15;
            uint4 v = *reinterpret_cast<const uint4*>(
                Bt + (size_t)(bn + row) * K + k0 + g * 8);
            *reinterpret_cast<uint4*>(smB + row * 256 + ((g ^ (row & 15)) * 16)) = v;
        }
        __syncthreads();

        #pragma unroll
        for (int kk = 0; kk < 4; ++kk) {
            bf16x8 af[MF], bfr[2];
            #pragma unroll
            for (int i = 0; i < MF; ++i) {
                int m = wm * (MF * 16) + i * 16 + lr;
                af[i] = *reinterpret_cast<const bf16x8*>(
                    smA + m * 256 + (((kk * 4 + lc) ^ (m & 15)) * 16));
            }
            #pragma unroll
            for (int j = 0; j < 2; ++j) {
                int n = wn * 32 + j * 16 + lr;
                bfr[j] = *reinterpret_cast<const bf16x8*>(
                    smB + n * 256 + (((kk * 4 + lc) ^ (n & 15)) * 16));
            }
            #pragma unroll
            for (int i = 0; i < MF; ++i)
                #pragma unroll
                for (int j = 0; j < 2; ++j)
                    acc[i][j] = __builtin_amdgcn_mfma_f32_16x16x32_bf16(
                        af[i], bfr[j], acc[i][j], 0, 0, 0);
        }
        __syncthreads();
    }

    #pragma unroll
    for (int i = 0; i < MF; ++i) {
        #pragma unroll
        for (int j = 0; j < 2; ++j) {
            int col = bn + wn * 32 + j * 16 + lr;
            #pragma unroll
            for (int r = 0; r < 4; ++r) {
                int row = bm + wm * (MF * 16) + i * 16 + lc * 4 + r;
                float val = acc[i][j][r] + bias[col];
                if constexpr (EPI == 2) {
                    const u16* e0 = (const u16*)extra0v;
                    val = bf2f(e0[(size_t)row * N + col]) + val * extra1[row];
                    ((u16*)Cv)[(size_t)row * N + col] = f2bf(val);
                } else if constexpr (EPI == 3) {
                    const u16* e0 = (const u16*)extra0v;
                    ((float*)Cv)[(size_t)row * N + col] = bf2f(e0[(size_t)row * N + col]) + val;
                } else {
                    ((u16*)Cv)[(size_t)row * N + col] = f2bf(val);
                }
            }
        }
    }
}

// ---------------------------------------------------------------------------
// ui-concat MFMA GEMM + tanh, BK=128: t = tanh([h|mixed|pb|summ] @ W1 + b1)
// ---------------------------------------------------------------------------
__global__ __launch_bounds__(256) void mm_ui_k(
    const u16* __restrict__ h, const u16* __restrict__ mixed,
    const u16* __restrict__ php, const u16* __restrict__ summ,
    const u16* __restrict__ W1t, const float* __restrict__ b1,
    u16* __restrict__ t)
{
    __shared__ __align__(16) unsigned char smem[32768];
    unsigned char* smA = smem;
    unsigned char* smB = smem + 16384;

    const int nb  = gridDim.x;
    const int per = nb >> 3;
    const int id  = blockIdx.x;
    const int nid = (id & 7) * per + (id >> 3);
    const int bx  = nid & 3, by = nid >> 2;

    const int tid  = threadIdx.x;
    const int lane = tid & 63, wid = tid >> 6;
    const int wm   = wid >> 1, wn = wid & 1;
    const int bm   = by * 64, bn = bx * 64;
    const int lr   = lane & 15, lc = lane >> 4;

    f32x4 acc[2][2] = {};

    for (int k0 = 0; k0 < 1024; k0 += 128) {
        const int seg = k0 >> 8, kb = k0 & 255;
        const u16* Asrc = (seg == 0) ? h : (seg == 1) ? mixed : (seg == 2) ? php : summ;
        #pragma unroll
        for (int i = 0; i < 4; ++i) {
            int e = tid + i * 256;
            int row = e >> 4, g = e & 15;
            int rs = bm + row;
            if (seg == 2) rs >>= 4;
            uint4 v = *reinterpret_cast<const uint4*>(
                Asrc + (size_t)rs * DS_ + kb + g * 8);
            *reinterpret_cast<uint4*>(smA + row * 256 + ((g ^ (row & 15)) * 16)) = v;
        }
        #pragma unroll
        for (int i = 0; i < 4; ++i) {
            int e = tid + i * 256;
            int row = e >> 4, g = e & 15;
            uint4 v = *reinterpret_cast<const uint4*>(
                W1t + (size_t)(bn + row) * 1024 + k0 + g * 8);
            *reinterpret_cast<uint4*>(smB + row * 256 + ((g ^ (row & 15)) * 16)) = v;
        }
        __syncthreads();

        #pragma unroll
        for (int kk = 0; kk < 4; ++kk) {
            bf16x8 af[2], bfr[2];
            #pragma unroll
            for (int i = 0; i < 2; ++i) {
                int m = wm * 32 + i * 16 + lr;
                af[i] = *reinterpret_cast<const bf16x8*>(
                    smA + m * 256 + (((kk * 4 + lc) ^ (m & 15)) * 16));
            }
            #pragma unroll
            for (int j = 0; j < 2; ++j) {
                int n = wn * 32 + j * 16 + lr;
                bfr[j] = *reinterpret_cast<const bf16x8*>(
                    smB + n * 256 + (((kk * 4 + lc) ^ (n & 15)) * 16));
            }
            #pragma unroll
            for (int i = 0; i < 2; ++i)
                #pragma unroll
                for (int j = 0; j < 2; ++j)
                    acc[i][j] = __builtin_amdgcn_mfma_f32_16x16x32_bf16(
                        af[i], bfr[j], acc[i][j], 0, 0, 0);
        }
        __syncthreads();
    }

    #pragma unroll
    for (int i = 0; i < 2; ++i) {
        #pragma unroll
        for (int j = 0; j < 2; ++j) {
            int col = bn + wn * 32 + j * 16 + lr;
            #pragma unroll
            for (int r = 0; r < 4; ++r) {
                int row = bm + wm * 32 + i * 16 + lc * 4 + r;
                t[(size_t)row * DS_ + col] = f2bf(tanhf(acc[i][j][r] + b1[col]));
            }
        }
    }
}

// ---------------------------------------------------------------------------
// Fused banded attention: per block = 32 tokens.
// Phase 1: stage Q[32][256] + K-window[96][256] bf16 in LDS (single barrier),
//          12 MFMA tile-pairs across 4 waves -> S band in LDS (aliases Q).
// Phase 2: each wave does top-8 select + softmax + V gather (L2) for 8 tokens.
// ---------------------------------------------------------------------------
__global__ __launch_bounds__(256) void attn_fused_k(
    const u16* __restrict__ qkv, u16* __restrict__ summ)
{
    __shared__ __align__(16) unsigned char smem[65536];  // Q 16KB | K 48KB
    unsigned char* smQ = smem;
    unsigned char* smK = smem + 16384;
    float* Sld = reinterpret_cast<float*>(smem);         // [32][97], aliases Q

    const int bid = blockIdx.x;                    // 256 blocks
    const int blk = (bid & 7) * 32 + (bid >> 3);   // XCD swizzle
    const int t0 = blk * 32;
    const int b  = t0 >> 11;
    const int s0 = t0 & (S_ - 1);
    const int tid = threadIdx.x;
    const int lane = tid & 63, wid = tid >> 6;
    const int lr = lane & 15, lc = lane >> 4;
    const int qt  = wid & 1;
    const int ktb = (wid >> 1) * 3;

    // ---- stage Q (32 rows x 512B) and K window (96 rows x 512B) ----
    #pragma unroll
    for (int i = 0; i < 4; ++i) {
        int e = tid + i * 256;
        int row = e >> 5, g = e & 31;
        uint4 v = *reinterpret_cast<const uint4*>(
            qkv + (size_t)(t0 + row) * 768 + g * 8);
        *reinterpret_cast<uint4*>(smQ + row * 512 + ((g ^ (row & 15)) * 16)) = v;
    }
    #pragma unroll
    for (int i = 0; i < 12; ++i) {
        int e = tid + i * 256;
        int row = e >> 5, g = e & 31;
        int krow = s0 - 64 + row; if (krow < 0) krow = 0;
        uint4 v = *reinterpret_cast<const uint4*>(
            qkv + ((size_t)(b * S_) + krow) * 768 + 256 + g * 8);
        *reinterpret_cast<uint4*>(smK + row * 512 + ((g ^ (row & 15)) * 16)) = v;
    }
    __syncthreads();

    // ---- MFMA: wave = (q-tile qt) x (k-tiles ktb..ktb+2), K=256 in 8 steps
    f32x4 acc[3] = {};
    #pragma unroll
    for (int ks = 0; ks < 8; ++ks) {
        bf16x8 af;
        {
            int m = qt * 16 + lr;
            af = *reinterpret_cast<const bf16x8*>(
                smQ + m * 512 + (((ks * 4 + lc) ^ (m & 15)) * 16));
        }
        #pragma unroll
        for (int j = 0; j < 3; ++j) {
            int n = (ktb + j) * 16 + lr;
            bf16x8 bv = *reinterpret_cast<const bf16x8*>(
                smK + n * 512 + (((ks * 4 + lc) ^ (n & 15)) * 16));
            acc[j] = __builtin_amdgcn_mfma_f32_16x16x32_bf16(af, bv, acc[j], 0, 0, 0);
        }
    }
    __syncthreads();   // all smQ reads done; Sld may overwrite it

    #pragma unroll
    for (int j = 0; j < 3; ++j) {
        int col = (ktb + j) * 16 + lr;
        #pragma unroll
        for (int r = 0; r < 4; ++r) {
            int row = qt * 16 + lc * 4 + r;
            Sld[row * 97 + col] = acc[j][r];
        }
    }
    __syncthreads();

    // ---- select phase: wave handles 8 tokens serially ----
    for (int u = 0; u < 8; ++u) {
        const int i = wid * 8 + u;
        const int m = t0 + i;
        const int s = s0 + i;

        float sc = (s - LB_ + lane >= 0) ? Sld[i * 97 + i + lane] * 0.0625f : -INFINITY;

        float vals[TOPK_]; int idxs[TOPK_];
        #pragma unroll
        for (int t = 0; t < TOPK_; ++t) {
            float mv = sc; int mi = lane;
            #pragma unroll
            for (int off = 32; off; off >>= 1) {
                float ov = __shfl_xor(mv, off);
                int   oi = __shfl_xor(mi, off);
                if (ov > mv || (ov == mv && oi < mi)) { mv = ov; mi = oi; }
            }
            vals[t] = mv; idxs[t] = mi;
            if (lane == mi) sc = -INFINITY;
        }

        const float mref = (vals[0] == -INFINITY) ? 0.f : vals[0];
        float ex[TOPK_], ssum = 0.f;
        #pragma unroll
        for (int t = 0; t < TOPK_; ++t) { ex[t] = expf(vals[t] - mref); ssum += ex[t]; }
        const float inv = 1.f / fmaxf(ssum, 1e-30f);

        // out[j] = dim lane*4+j ; V row gathered from global (L2-hot)
        float out0 = 0.f, out1 = 0.f, out2 = 0.f, out3 = 0.f;
        #pragma unroll
        for (int t = 0; t < TOPK_; ++t) {
            float wt = ex[t] * inv;
            int tok = s - LB_ + idxs[t];
            tok = min(max(tok, 0), S_ - 1);
            bf16x4 vv = *reinterpret_cast<const bf16x4*>(
                qkv + ((size_t)(b * S_) + tok) * 768 + 512 + lane * 4);
            out0 += wt * (float)vv[0];
            out1 += wt * (float)vv[1];
            out2 += wt * (float)vv[2];
            out3 += wt * (float)vv[3];
        }
        ushort4 pk;
        pk.x = f2bf(out0); pk.y = f2bf(out1); pk.z = f2bf(out2); pk.w = f2bf(out3);
        *reinterpret_cast<ushort4*>(summ + (size_t)m * DS_ + lane * 4) = pk;
    }
}

// ---------------------------------------------------------------------------
// Causal depthwise conv (K=5) + chunk mean + halt gate + fused php projection.
// One block per (b, chunk of 16); thread = channel d. XCD-swizzled grid.
// php[chunk,n] = sum_k cmean[k] * Wp[k,n] + bp[n]  (Wpt is [N][K])
// ---------------------------------------------------------------------------
__global__ __launch_bounds__(256) void conv_pool_k(
    const u16* __restrict__ h, const float* __restrict__ conv_w,
    const float* __restrict__ conv_b, const float* __restrict__ Wh,
    const float* __restrict__ bh, const u16* __restrict__ Wpt,
    const float* __restrict__ bp, u16* __restrict__ mixed,
    u16* __restrict__ php, float* __restrict__ gate)
{
    __shared__ float gpart[16][4];
    __shared__ float cm[256];
    const int bid = blockIdx.x;
    const int blk = (bid & 7) * 64 + (bid >> 3);   // XCD swizzle (8 x 64)
    const int d = threadIdx.x;
    const int b = blk >> 7;
    const int s0 = (blk & 127) * 16;
    const u16* hb = h + (size_t)b * S_ * DS_;
    u16* mb = mixed + (size_t)b * S_ * DS_;

    const float w0 = conv_w[0 * DS_ + d], w1 = conv_w[1 * DS_ + d],
                w2 = conv_w[2 * DS_ + d], w3 = conv_w[3 * DS_ + d],
                w4 = conv_w[4 * DS_ + d];
    const float cb = conv_b[d];
    const float whd = Wh[d * 3 + 2];

    float a0 = (s0 >= 4) ? bf2f(hb[(size_t)(s0 - 4) * DS_ + d]) : 0.f;
    float a1 = (s0 >= 3) ? bf2f(hb[(size_t)(s0 - 3) * DS_ + d]) : 0.f;
    float a2 = (s0 >= 2) ? bf2f(hb[(size_t)(s0 - 2) * DS_ + d]) : 0.f;
    float a3 = (s0 >= 1) ? bf2f(hb[(size_t)(s0 - 1) * DS_ + d]) : 0.f;

    float sum = 0.f;
    #pragma unroll
    for (int tt = 0; tt < 16; ++tt) {
        int s = s0 + tt;
        float cur = bf2f(hb[(size_t)s * DS_ + d]);
        mb[(size_t)s * DS_ + d] = f2bf(w0 * a0 + w1 * a1 + w2 * a2 + w3 * a3 + w4 * cur + cb);
        sum += cur;
        float g = cur * whd;
        #pragma unroll
        for (int off = 32; off; off >>= 1) g += __shfl_down(g, off);
        if ((d & 63) == 0) gpart[tt][d >> 6] = g;
        a0 = a1; a1 = a2; a2 = a3; a3 = cur;
    }
    cm[d] = sum * (1.f / 16.f);
    __syncthreads();
    if (d < 16) {
        float gg = gpart[d][0] + gpart[d][1] + gpart[d][2] + gpart[d][3];
        gate[(size_t)b * S_ + s0 + d] = 1.f / (1.f + expf(-(gg + bh[2])));
    }
    // php projection: thread d computes output column d
    float accp = bp[d];
    const u16* wr = Wpt + (size_t)d * 256;
    #pragma unroll
    for (int k = 0; k < 256; k += 8) {
        bf16x8 w8 = *reinterpret_cast<const bf16x8*>(wr + k);
        accp += cm[k]     * (float)w8[0] + cm[k + 1] * (float)w8[1]
              + cm[k + 2] * (float)w8[2] + cm[k + 3] * (float)w8[3]
              + cm[k + 4] * (float)w8[4] + cm[k + 5] * (float)w8[5]
              + cm[k + 6] * (float)w8[6] + cm[k + 7] * (float)w8[7];
    }
    php[(size_t)blk * DS_ + d] = f2bf(accp);
}

// ---------------------------------------------------------------------------
// Merged prep: blocks 0..4095 cvt x->bf16; 4096..5183 weight transposes;
// 5184 qkv bias concat.
// ---------------------------------------------------------------------------
__global__ __launch_bounds__(256) void prep_all_k(
    const float* __restrict__ x,
    const float* __restrict__ Wi, const float* __restrict__ Wq,
    const float* __restrict__ Wk, const float* __restrict__ Wv,
    const float* __restrict__ Wp, const float* __restrict__ W1,
    const float* __restrict__ W2, const float* __restrict__ Wo,
    const float* __restrict__ bq, const float* __restrict__ bk,
    const float* __restrict__ bv,
    u16* __restrict__ xb,
    u16* __restrict__ Wit, u16* __restrict__ Wqkvt, u16* __restrict__ Wpt,
    u16* __restrict__ W1t, u16* __restrict__ W2t, u16* __restrict__ Wot,
    float* __restrict__ bqkv)
{
    const int bid0 = blockIdx.x;
    if (bid0 < 4096) {
        int i = (bid0 * 256 + threadIdx.x) * 8;
        float4 a = *reinterpret_cast<const float4*>(x + i);
        float4 b = *reinterpret_cast<const float4*>(x + i + 4);
        uint4 g;
        g.x = pack2(a.x, a.y); g.y = pack2(a.z, a.w);
        g.z = pack2(b.x, b.y); g.w = pack2(b.z, b.w);
        *reinterpret_cast<uint4*>(xb + i) = g;
        return;
    }
    const int bid = bid0 - 4096;
    if (bid >= 1088) {
        for (int i = threadIdx.x; i < 768; i += 256) {
            float v = (i < 256) ? bq[i] : (i < 512) ? bk[i - 256] : bv[i - 512];
            bqkv[i] = v;
        }
        return;
    }
    const float* in; u16* out; int K, N, t;
    if (bid < 256)      { in = Wi; out = Wit;             K = 1024; N = 256;  t = bid; }
    else if (bid < 320) { in = Wq; out = Wqkvt;           K = 256;  N = 256;  t = bid - 256; }
    else if (bid < 384) { in = Wk; out = Wqkvt + 256*256; K = 256;  N = 256;  t = bid - 320; }
    else if (bid < 448) { in = Wv; out = Wqkvt + 512*256; K = 256;  N = 256;  t = bid - 384; }
    else if (bid < 512) { in = Wp; out = Wpt;             K = 256;  N = 256;  t = bid - 448; }
    else if (bid < 768) { in = W1; out = W1t;             K = 1024; N = 256;  t = bid - 512; }
    else if (bid < 832) { in = W2; out = W2t;             K = 256;  N = 256;  t = bid - 768; }
    else                { in = Wo; out = Wot;             K = 256;  N = 1024; t = bid - 832; }
    const int tilesX = N >> 5;
    const int n0 = (t % tilesX) * 32, k0 = (t / tilesX) * 32;
    __shared__ float tl[32][33];
    const int cx = threadIdx.x & 31, cy = threadIdx.x >> 5;
    #pragma unroll
    for (int r = 0; r < 32; r += 8)
        tl[cy + r][cx] = in[(size_t)(k0 + cy + r) * N + n0 + cx];
    __syncthreads();
    #pragma unroll
    for (int r = 0; r < 32; r += 8)
        out[(size_t)(n0 + cy + r) * K + k0 + cx] = f2bf(tl[cx][cy + r]);
}

// ---------------------------------------------------------------------------
extern "C" void kernel_launch(void* const* d_in, const int* in_sizes, int n_in,
                              void* d_out, int out_size, void* d_ws, size_t ws_size,
                              hipStream_t stream)
{
    const float* x      = (const float*)d_in[0];
    const float* Wi     = (const float*)d_in[1];
    const float* bi     = (const float*)d_in[2];
    const float* conv_w = (const float*)d_in[3];
    const float* conv_b = (const float*)d_in[4];
    const float* Wp     = (const float*)d_in[5];
    const float* bp     = (const float*)d_in[6];
    const float* Wh     = (const float*)d_in[7];
    const float* bh     = (const float*)d_in[8];
    const float* Wq     = (const float*)d_in[9];
    const float* bq     = (const float*)d_in[10];
    const float* Wk     = (const float*)d_in[11];
    const float* bk     = (const float*)d_in[12];
    const float* Wv     = (const float*)d_in[13];
    const float* bv     = (const float*)d_in[14];
    const float* W1     = (const float*)d_in[15];
    const float* b1     = (const float*)d_in[16];
    const float* W2     = (const float*)d_in[17];
    const float* b2     = (const float*)d_in[18];
    const float* Wo     = (const float*)d_in[19];
    const float* bo     = (const float*)d_in[20];
    float* out = (float*)d_out;

    char* p = (char*)d_ws;
    auto alloc = [&](size_t bytes) { char* r = p; p += (bytes + 255) & ~(size_t)255; return r; };

    u16*  xb     = (u16*)alloc((size_t)BS_ * DM_ * 2);
    u16*  h      = (u16*)alloc((size_t)BS_ * DS_ * 2);
    u16*  mixed  = (u16*)alloc((size_t)BS_ * DS_ * 2);
    u16*  qkv    = (u16*)alloc((size_t)BS_ * 768 * 2);
    u16*  sm     = (u16*)alloc((size_t)BS_ * DS_ * 2);
    u16*  tb     = (u16*)alloc((size_t)BS_ * DS_ * 2);
    u16*  php    = (u16*)alloc((size_t)512 * DS_ * 2);
    float* gate  = (float*)alloc((size_t)BS_ * 4);
    float* bqkv  = (float*)alloc(768 * 4);
    u16* Wit     = (u16*)alloc((size_t)256 * 1024 * 2);
    u16* Wqkvt   = (u16*)alloc((size_t)768 * 256 * 2);
    u16* Wpt     = (u16*)alloc((size_t)256 * 256 * 2);
    u16* W1t     = (u16*)alloc((size_t)256 * 1024 * 2);
    u16* W2t     = (u16*)alloc((size_t)256 * 256 * 2);
    u16* Wot     = (u16*)alloc((size_t)1024 * 256 * 2);

    dim3 blk(256);

    // ---- prep (cvt x + all weight transposes + bias concat) ----
    prep_all_k<<<5185, blk, 0, stream>>>(x, Wi, Wq, Wk, Wv, Wp, W1, W2, Wo,
                                         bq, bk, bv, xb,
                                         Wit, Wqkvt, Wpt, W1t, W2t, Wot, bqkv);

    // ---- forward ----
    // h = x @ Wi + bi
    mm_k<2, 0><<<512, blk, 0, stream>>>(xb, Wit, bi, h, BS_, DM_, DS_, 4, nullptr, nullptr);

    for (int step = 0; step < 2; ++step) {
        conv_pool_k<<<512, blk, 0, stream>>>(h, conv_w, conv_b, Wh, bh, Wpt, bp,
                                             mixed, php, gate);
        mm_k<4, 0><<<768, blk, 0, stream>>>(h, Wqkvt, bqkv, qkv, BS_, DS_, 768, 12, nullptr, nullptr);
        attn_fused_k<<<256, blk, 0, stream>>>(qkv, sm);
        mm_ui_k<<<512, blk, 0, stream>>>(h, mixed, php, sm, W1t, b1, tb);
        // h = h + (tanh(ui@W1+b1) @ W2 + b2) * gate
        mm_k<2, 2><<<512, blk, 0, stream>>>(tb, W2t, b2, h, BS_, DS_, DS_, 4, h, gate);
    }

    // out = x + h @ Wo + bo
    mm_k<4, 3><<<1024, blk, 0, stream>>>(h, Wot, bo, out, BS_, DS_, DM_, 16, xb, nullptr);
}

// Round 8
// 156.044 us; speedup vs baseline: 1.4541x; 1.4541x over previous
//
#include <hip/hip_runtime.h>
#include <math.h>

#define B_    4
#define S_    2048
#define BS_   8192       // B_*S_
#define DM_   1024
#define DS_   256
#define LB_   64
#define TOPK_ 8

typedef unsigned short u16;
typedef __bf16 bf16x8 __attribute__((ext_vector_type(8)));
typedef float  f32x4  __attribute__((ext_vector_type(4)));

static __device__ __forceinline__ u16 f2bf(float f) {
    union { float f; unsigned u; } a; a.f = f;
    unsigned u = a.u;
    unsigned r = u + 0x7FFFu + ((u >> 16) & 1u);   // RNE
    return (u16)(r >> 16);
}
static __device__ __forceinline__ float bf2f(u16 v) {
    union { unsigned u; float f; } a; a.u = ((unsigned)v) << 16; return a.f;
}
static __device__ __forceinline__ unsigned pack2(float a, float b) {
    return (unsigned)f2bf(a) | ((unsigned)f2bf(b) << 16);
}
// 16B-granule swizzle within a 64B row (4 granules) -- scores_k staging
static __device__ __forceinline__ int swz(int row, int cb) {
    return (cb ^ (row & 3) ^ ((row >> 2) & 3)) & 3;
}

// async global->LDS, 16B per lane; LDS dest = uniform base + lane*16
#define GLD16(g, l) __builtin_amdgcn_global_load_lds(                         \
    (const __attribute__((address_space(1))) void*)(g),                       \
    (__attribute__((address_space(3))) void*)(l), 16, 0, 0)

// ---------------------------------------------------------------------------
// MFMA bf16 GEMM body, BK=128: C = epi(A_bf16[M,K] @ Bt_bf16[N,K]^T + bias)
// MF = M-frags/wave (2 -> BM=64, 4 -> BM=128). BN=64. 4 waves (2x2).
// Staging via global_load_lds: linear LDS dest, source granule pre-swizzled
// lg ^ (row&15); fragment reads apply the same involution.
// EPI: 0 -> C bf16 | 2 -> C bf16 = extra0_bf16 + val*extra1[m]
//      3 -> C f32  = extra0_bf16 + val.
// ---------------------------------------------------------------------------
template<int MF, int EPI>
__device__ __forceinline__ void mm_dev(
    unsigned char* smem, int id, int nb, int gx,
    const u16* __restrict__ A, const u16* __restrict__ Bt,
    const float* __restrict__ bias, void* __restrict__ Cv,
    int K, int N,
    const void* __restrict__ extra0v, const float* __restrict__ extra1)
{
    constexpr int BM = MF * 32;
    unsigned char* smA = smem;
    unsigned char* smB = smem + BM * 256;

    const int per = nb >> 3;
    const int nid = (id & 7) * per + (id >> 3);   // bijective XCD chunking
    const int bx  = nid % gx, by = nid / gx;

    const int tid  = threadIdx.x;
    const int lane = tid & 63, wid = tid >> 6;
    const int wm   = wid >> 1, wn = wid & 1;
    const int bm   = by * BM, bn = bx * 64;
    const int lr   = lane & 15, lc = lane >> 4;
    const int l16  = lane >> 4, lg = lane & 15;

    f32x4 acc[MF][2] = {};

    for (int k0 = 0; k0 < K; k0 += 128) {
        // stage A: wave w covers rows [w*BM/4, +BM/4), 4 rows per gld op
        #pragma unroll
        for (int t = 0; t < BM / 16; ++t) {
            int row = wid * (BM / 4) + t * 4 + l16;
            int gg  = lg ^ (row & 15);
            GLD16(A + (size_t)(bm + row) * K + k0 + gg * 8,
                  smA + (size_t)(wid * (BM / 4) + t * 4) * 256);
        }
        // stage B: 64 rows
        #pragma unroll
        for (int t = 0; t < 4; ++t) {
            int row = wid * 16 + t * 4 + l16;
            int gg  = lg ^ (row & 15);
            GLD16(Bt + (size_t)(bn + row) * K + k0 + gg * 8,
                  smB + (size_t)(wid * 16 + t * 4) * 256);
        }
        __syncthreads();   // drains vmcnt (gld) before fragment reads

        #pragma unroll
        for (int kk = 0; kk < 4; ++kk) {
            bf16x8 af[MF], bfr[2];
            #pragma unroll
            for (int i = 0; i < MF; ++i) {
                int m = wm * (MF * 16) + i * 16 + lr;
                af[i] = *reinterpret_cast<const bf16x8*>(
                    smA + m * 256 + (((kk * 4 + lc) ^ (m & 15)) * 16));
            }
            #pragma unroll
            for (int j = 0; j < 2; ++j) {
                int n = wn * 32 + j * 16 + lr;
                bfr[j] = *reinterpret_cast<const bf16x8*>(
                    smB + n * 256 + (((kk * 4 + lc) ^ (n & 15)) * 16));
            }
            #pragma unroll
            for (int i = 0; i < MF; ++i)
                #pragma unroll
                for (int j = 0; j < 2; ++j)
                    acc[i][j] = __builtin_amdgcn_mfma_f32_16x16x32_bf16(
                        af[i], bfr[j], acc[i][j], 0, 0, 0);
        }
        __syncthreads();
    }

    #pragma unroll
    for (int i = 0; i < MF; ++i) {
        #pragma unroll
        for (int j = 0; j < 2; ++j) {
            int col = bn + wn * 32 + j * 16 + lr;
            #pragma unroll
            for (int r = 0; r < 4; ++r) {
                int row = bm + wm * (MF * 16) + i * 16 + lc * 4 + r;
                float val = acc[i][j][r] + bias[col];
                if constexpr (EPI == 2) {
                    const u16* e0 = (const u16*)extra0v;
                    val = bf2f(e0[(size_t)row * N + col]) + val * extra1[row];
                    ((u16*)Cv)[(size_t)row * N + col] = f2bf(val);
                } else if constexpr (EPI == 3) {
                    const u16* e0 = (const u16*)extra0v;
                    ((float*)Cv)[(size_t)row * N + col] = bf2f(e0[(size_t)row * N + col]) + val;
                } else {
                    ((u16*)Cv)[(size_t)row * N + col] = f2bf(val);
                }
            }
        }
    }
}

template<int MF, int EPI>
__global__ __launch_bounds__(256) void mm_k(
    const u16* __restrict__ A, const u16* __restrict__ Bt,
    const float* __restrict__ bias, void* __restrict__ Cv,
    int K, int N, int gx,
    const void* __restrict__ extra0v, const float* __restrict__ extra1)
{
    __shared__ __align__(16) unsigned char smem[MF * 32 * 256 + 64 * 256];
    mm_dev<MF, EPI>(smem, blockIdx.x, gridDim.x, gx, A, Bt, bias, Cv, K, N,
                    extra0v, extra1);
}

// ---------------------------------------------------------------------------
// ui-concat MFMA GEMM + tanh, BK=128: t = tanh([h|mixed|pb|summ] @ W1 + b1)
// K=1024 (4 bf16 segments of 256), pb[m,:] = php[m>>4,:]. BM=64.
// ---------------------------------------------------------------------------
__global__ __launch_bounds__(256) void mm_ui_k(
    const u16* __restrict__ h, const u16* __restrict__ mixed,
    const u16* __restrict__ php, const u16* __restrict__ summ,
    const u16* __restrict__ W1t, const float* __restrict__ b1,
    u16* __restrict__ t)
{
    __shared__ __align__(16) unsigned char smem[32768];
    unsigned char* smA = smem;
    unsigned char* smB = smem + 16384;

    const int nb  = gridDim.x;
    const int per = nb >> 3;
    const int id  = blockIdx.x;
    const int nid = (id & 7) * per + (id >> 3);
    const int bx  = nid & 3, by = nid >> 2;

    const int tid  = threadIdx.x;
    const int lane = tid & 63, wid = tid >> 6;
    const int wm   = wid >> 1, wn = wid & 1;
    const int bm   = by * 64, bn = bx * 64;
    const int lr   = lane & 15, lc = lane >> 4;
    const int l16  = lane >> 4, lg = lane & 15;

    f32x4 acc[2][2] = {};

    for (int k0 = 0; k0 < 1024; k0 += 128) {
        const int seg = k0 >> 8, kb = k0 & 255;
        const u16* Asrc = (seg == 0) ? h : (seg == 1) ? mixed : (seg == 2) ? php : summ;
        #pragma unroll
        for (int t = 0; t < 4; ++t) {
            int row = wid * 16 + t * 4 + l16;
            int gg  = lg ^ (row & 15);
            int rs  = bm + row;
            if (seg == 2) rs >>= 4;
            GLD16(Asrc + (size_t)rs * DS_ + kb + gg * 8,
                  smA + (size_t)(wid * 16 + t * 4) * 256);
        }
        #pragma unroll
        for (int t = 0; t < 4; ++t) {
            int row = wid * 16 + t * 4 + l16;
            int gg  = lg ^ (row & 15);
            GLD16(W1t + (size_t)(bn + row) * 1024 + k0 + gg * 8,
                  smB + (size_t)(wid * 16 + t * 4) * 256);
        }
        __syncthreads();

        #pragma unroll
        for (int kk = 0; kk < 4; ++kk) {
            bf16x8 af[2], bfr[2];
            #pragma unroll
            for (int i = 0; i < 2; ++i) {
                int m = wm * 32 + i * 16 + lr;
                af[i] = *reinterpret_cast<const bf16x8*>(
                    smA + m * 256 + (((kk * 4 + lc) ^ (m & 15)) * 16));
            }
            #pragma unroll
            for (int j = 0; j < 2; ++j) {
                int n = wn * 32 + j * 16 + lr;
                bfr[j] = *reinterpret_cast<const bf16x8*>(
                    smB + n * 256 + (((kk * 4 + lc) ^ (n & 15)) * 16));
            }
            #pragma unroll
            for (int i = 0; i < 2; ++i)
                #pragma unroll
                for (int j = 0; j < 2; ++j)
                    acc[i][j] = __builtin_amdgcn_mfma_f32_16x16x32_bf16(
                        af[i], bfr[j], acc[i][j], 0, 0, 0);
        }
        __syncthreads();
    }

    #pragma unroll
    for (int i = 0; i < 2; ++i) {
        #pragma unroll
        for (int j = 0; j < 2; ++j) {
            int col = bn + wn * 32 + j * 16 + lr;
            #pragma unroll
            for (int r = 0; r < 4; ++r) {
                int row = bm + wm * 32 + i * 16 + lc * 4 + r;
                t[(size_t)row * DS_ + col] = f2bf(tanhf(acc[i][j][r] + b1[col]));
            }
        }
    }
}

// ---------------------------------------------------------------------------
// Causal depthwise conv (K=5) + chunk mean + halt gate + fused php projection.
// ---------------------------------------------------------------------------
__device__ __forceinline__ void conv_dev(
    unsigned char* smem, int cid,
    const u16* __restrict__ h, const float* __restrict__ conv_w,
    const float* __restrict__ conv_b, const float* __restrict__ Wh,
    const float* __restrict__ bh, const u16* __restrict__ Wpt,
    const float* __restrict__ bp, u16* __restrict__ mixed,
    u16* __restrict__ php, float* __restrict__ gate)
{
    float* gpart = (float*)smem;            // [16][4]
    float* cm    = (float*)(smem + 256);    // [256]
    const int blk = (cid & 7) * 64 + (cid >> 3);   // XCD swizzle (8 x 64)
    const int d = threadIdx.x;
    const int b = blk >> 7;
    const int s0 = (blk & 127) * 16;
    const u16* hb = h + (size_t)b * S_ * DS_;
    u16* mb = mixed + (size_t)b * S_ * DS_;

    const float w0 = conv_w[0 * DS_ + d], w1 = conv_w[1 * DS_ + d],
                w2 = conv_w[2 * DS_ + d], w3 = conv_w[3 * DS_ + d],
                w4 = conv_w[4 * DS_ + d];
    const float cb = conv_b[d];
    const float whd = Wh[d * 3 + 2];

    float a0 = (s0 >= 4) ? bf2f(hb[(size_t)(s0 - 4) * DS_ + d]) : 0.f;
    float a1 = (s0 >= 3) ? bf2f(hb[(size_t)(s0 - 3) * DS_ + d]) : 0.f;
    float a2 = (s0 >= 2) ? bf2f(hb[(size_t)(s0 - 2) * DS_ + d]) : 0.f;
    float a3 = (s0 >= 1) ? bf2f(hb[(size_t)(s0 - 1) * DS_ + d]) : 0.f;

    float sum = 0.f;
    #pragma unroll
    for (int tt = 0; tt < 16; ++tt) {
        int s = s0 + tt;
        float cur = bf2f(hb[(size_t)s * DS_ + d]);
        mb[(size_t)s * DS_ + d] = f2bf(w0 * a0 + w1 * a1 + w2 * a2 + w3 * a3 + w4 * cur + cb);
        sum += cur;
        float g = cur * whd;
        #pragma unroll
        for (int off = 32; off; off >>= 1) g += __shfl_down(g, off);
        if ((d & 63) == 0) gpart[tt * 4 + (d >> 6)] = g;
        a0 = a1; a1 = a2; a2 = a3; a3 = cur;
    }
    cm[d] = sum * (1.f / 16.f);
    __syncthreads();
    if (d < 16) {
        float gg = gpart[d * 4 + 0] + gpart[d * 4 + 1] + gpart[d * 4 + 2] + gpart[d * 4 + 3];
        gate[(size_t)b * S_ + s0 + d] = 1.f / (1.f + expf(-(gg + bh[2])));
    }
    // php projection: thread d computes output column d
    float accp = bp[d];
    const u16* wr = Wpt + (size_t)d * 256;
    #pragma unroll
    for (int k = 0; k < 256; k += 8) {
        bf16x8 w8 = *reinterpret_cast<const bf16x8*>(wr + k);
        accp += cm[k]     * (float)w8[0] + cm[k + 1] * (float)w8[1]
              + cm[k + 2] * (float)w8[2] + cm[k + 3] * (float)w8[3]
              + cm[k + 4] * (float)w8[4] + cm[k + 5] * (float)w8[5]
              + cm[k + 6] * (float)w8[6] + cm[k + 7] * (float)w8[7];
    }
    php[(size_t)blk * DS_ + d] = f2bf(accp);
}

// ---------------------------------------------------------------------------
// Packed launch: blocks 0..767 qkv GEMM (MF=4, N=768); 768..1279 conv+php.
// Independent (both only read h); 768 % 8 == 0 keeps XCD mapping intact.
// ---------------------------------------------------------------------------
__global__ __launch_bounds__(256) void step_a_k(
    const u16* __restrict__ h, const u16* __restrict__ Wqkvt,
    const float* __restrict__ bqkv, u16* __restrict__ qkv,
    const float* __restrict__ conv_w, const float* __restrict__ conv_b,
    const float* __restrict__ Wh, const float* __restrict__ bh,
    const u16* __restrict__ Wpt, const float* __restrict__ bp,
    u16* __restrict__ mixed, u16* __restrict__ php, float* __restrict__ gate)
{
    __shared__ __align__(16) unsigned char smem[49152];
    if (blockIdx.x < 768) {
        mm_dev<4, 0>(smem, blockIdx.x, 768, 12, h, Wqkvt, bqkv, qkv,
                     DS_, 768, nullptr, nullptr);
    } else {
        conv_dev(smem, blockIdx.x - 768, h, conv_w, conv_b, Wh, bh,
                 Wpt, bp, mixed, php, gate);
    }
}

// ---------------------------------------------------------------------------
// Banded scores via MFMA: scores[t, l] = (q[t] . k[t-64+l]) * scale, f32 out.
// ---------------------------------------------------------------------------
__global__ __launch_bounds__(256) void scores_k(
    const u16* __restrict__ qkv, float* __restrict__ scores)
{
    __shared__ __align__(16) unsigned char smem[32 * 64 + 96 * 64];
    __shared__ float Sld[32][97];
    unsigned char* smA = smem;            // Q chunk: 32 rows x 32 bf16
    unsigned char* smB = smem + 32 * 64;  // K chunk: 96 rows x 32 bf16

    const int bid = blockIdx.x;                    // 256 blocks
    const int blk = (bid & 7) * 32 + (bid >> 3);   // XCD swizzle (8 x 32)
    const int t0 = blk * 32;
    const int b  = t0 >> 11;
    const int s0 = t0 & (S_ - 1);
    const int tid = threadIdx.x;
    const int lane = tid & 63, wid = tid >> 6;
    const int lr = lane & 15, lc = lane >> 4;
    const int qt  = wid & 1;
    const int ktb = (wid >> 1) * 3;

    const u16* qbase = qkv + (size_t)t0 * 768;
    const u16* kbase = qkv + (size_t)b * S_ * 768 + 256;

    f32x4 acc[3] = {};

    for (int k0 = 0; k0 < 256; k0 += 32) {
        #pragma unroll
        for (int i = 0; i < 2; ++i) {
            int e = tid + i * 256;
            const u16* src;
            unsigned char* dst;
            if (e < 128) {
                int row = e >> 2, cb = e & 3;
                src = qbase + (size_t)row * 768 + k0 + cb * 8;
                dst = smA + row * 64 + swz(row, cb) * 16;
            } else {
                int eb = e - 128;
                int row = eb >> 2, cb = eb & 3;
                int krow = s0 - 64 + row;
                if (krow < 0) krow = 0;
                src = kbase + (size_t)krow * 768 + k0 + cb * 8;
                dst = smB + row * 64 + swz(row, cb) * 16;
            }
            *reinterpret_cast<uint4*>(dst) = *reinterpret_cast<const uint4*>(src);
        }
        __syncthreads();

        bf16x8 af, bfr[3];
        {
            int m = qt * 16 + lr;
            af = *reinterpret_cast<const bf16x8*>(smA + m * 64 + swz(m, lc) * 16);
        }
        #pragma unroll
        for (int j = 0; j < 3; ++j) {
            int n = (ktb + j) * 16 + lr;
            bfr[j] = *reinterpret_cast<const bf16x8*>(smB + n * 64 + swz(n, lc) * 16);
        }
        #pragma unroll
        for (int j = 0; j < 3; ++j)
            acc[j] = __builtin_amdgcn_mfma_f32_16x16x32_bf16(af, bfr[j], acc[j], 0, 0, 0);
        __syncthreads();
    }

    #pragma unroll
    for (int j = 0; j < 3; ++j) {
        int col = (ktb + j) * 16 + lr;
        #pragma unroll
        for (int r = 0; r < 4; ++r) {
            int row = qt * 16 + lc * 4 + r;
            Sld[row][col] = acc[j][r];
        }
    }
    __syncthreads();

    #pragma unroll
    for (int it = 0; it < 8; ++it) {
        int e = tid + it * 256;
        int i = e >> 6, l = e & 63;
        scores[(size_t)(t0 + i) * 64 + l] = Sld[i][i + l] * 0.0625f;
    }
}

// ---------------------------------------------------------------------------
// Top-8 select + softmax + V-sum. scores f32, V bf16 (from qkv), summ bf16.
// ---------------------------------------------------------------------------
__global__ __launch_bounds__(256) void select_k(
    const float* __restrict__ scores, const u16* __restrict__ qkv,
    u16* __restrict__ summ)
{
    const int bid = blockIdx.x;                       // 2048 blocks
    const int sb  = (bid & 7) * 256 + (bid >> 3);     // bijective XCD swizzle
    const int m   = sb * 4 + (threadIdx.x >> 6);
    const int b = m >> 11;
    const int s = m & (S_ - 1);
    const int lane = threadIdx.x & 63;

    float sc = (s - LB_ + lane >= 0) ? scores[(size_t)m * 64 + lane] : -INFINITY;

    float vals[TOPK_]; int idxs[TOPK_];
    #pragma unroll
    for (int t = 0; t < TOPK_; ++t) {
        float mv = sc; int mi = lane;
        #pragma unroll
        for (int off = 32; off; off >>= 1) {
            float ov = __shfl_xor(mv, off);
            int   oi = __shfl_xor(mi, off);
            if (ov > mv || (ov == mv && oi < mi)) { mv = ov; mi = oi; }
        }
        vals[t] = mv; idxs[t] = mi;
        if (lane == mi) sc = -INFINITY;
    }

    const float mref = (vals[0] == -INFINITY) ? 0.f : vals[0];
    float e[TOPK_], ssum = 0.f;
    #pragma unroll
    for (int t = 0; t < TOPK_; ++t) { e[t] = expf(vals[t] - mref); ssum += e[t]; }
    const float inv = 1.f / fmaxf(ssum, 1e-30f);

    float out[4] = {0.f, 0.f, 0.f, 0.f};
    #pragma unroll
    for (int t = 0; t < TOPK_; ++t) {
        float wt = e[t] * inv;
        int tok = s - LB_ + idxs[t];
        tok = min(max(tok, 0), S_ - 1);
        const u16* vr = qkv + ((size_t)(b * S_) + tok) * 768 + 512;
        #pragma unroll
        for (int i = 0; i < 4; ++i) out[i] += wt * bf2f(vr[lane + i * 64]);
    }
    #pragma unroll
    for (int i = 0; i < 4; ++i)
        summ[(size_t)m * DS_ + lane + i * 64] = f2bf(out[i]);
}

// ---------------------------------------------------------------------------
// Merged prep: blocks 0..4095 cvt x->bf16; 4096..5183 weight transposes;
// 5184 qkv bias concat.
// ---------------------------------------------------------------------------
__global__ __launch_bounds__(256) void prep_all_k(
    const float* __restrict__ x,
    const float* __restrict__ Wi, const float* __restrict__ Wq,
    const float* __restrict__ Wk, const float* __restrict__ Wv,
    const float* __restrict__ Wp, const float* __restrict__ W1,
    const float* __restrict__ W2, const float* __restrict__ Wo,
    const float* __restrict__ bq, const float* __restrict__ bk,
    const float* __restrict__ bv,
    u16* __restrict__ xb,
    u16* __restrict__ Wit, u16* __restrict__ Wqkvt, u16* __restrict__ Wpt,
    u16* __restrict__ W1t, u16* __restrict__ W2t, u16* __restrict__ Wot,
    float* __restrict__ bqkv)
{
    const int bid0 = blockIdx.x;
    if (bid0 < 4096) {
        int i = (bid0 * 256 + threadIdx.x) * 8;
        float4 a = *reinterpret_cast<const float4*>(x + i);
        float4 b = *reinterpret_cast<const float4*>(x + i + 4);
        uint4 g;
        g.x = pack2(a.x, a.y); g.y = pack2(a.z, a.w);
        g.z = pack2(b.x, b.y); g.w = pack2(b.z, b.w);
        *reinterpret_cast<uint4*>(xb + i) = g;
        return;
    }
    const int bid = bid0 - 4096;
    if (bid >= 1088) {
        for (int i = threadIdx.x; i < 768; i += 256) {
            float v = (i < 256) ? bq[i] : (i < 512) ? bk[i - 256] : bv[i - 512];
            bqkv[i] = v;
        }
        return;
    }
    const float* in; u16* out; int K, N, t;
    if (bid < 256)      { in = Wi; out = Wit;             K = 1024; N = 256;  t = bid; }
    else if (bid < 320) { in = Wq; out = Wqkvt;           K = 256;  N = 256;  t = bid - 256; }
    else if (bid < 384) { in = Wk; out = Wqkvt + 256*256; K = 256;  N = 256;  t = bid - 320; }
    else if (bid < 448) { in = Wv; out = Wqkvt + 512*256; K = 256;  N = 256;  t = bid - 384; }
    else if (bid < 512) { in = Wp; out = Wpt;             K = 256;  N = 256;  t = bid - 448; }
    else if (bid < 768) { in = W1; out = W1t;             K = 1024; N = 256;  t = bid - 512; }
    else if (bid < 832) { in = W2; out = W2t;             K = 256;  N = 256;  t = bid - 768; }
    else                { in = Wo; out = Wot;             K = 256;  N = 1024; t = bid - 832; }
    const int tilesX = N >> 5;
    const int n0 = (t % tilesX) * 32, k0 = (t / tilesX) * 32;
    __shared__ float tl[32][33];
    const int cx = threadIdx.x & 31, cy = threadIdx.x >> 5;
    #pragma unroll
    for (int r = 0; r < 32; r += 8)
        tl[cy + r][cx] = in[(size_t)(k0 + cy + r) * N + n0 + cx];
    __syncthreads();
    #pragma unroll
    for (int r = 0; r < 32; r += 8)
        out[(size_t)(n0 + cy + r) * K + k0 + cx] = f2bf(tl[cx][cy + r]);
}

// ---------------------------------------------------------------------------
extern "C" void kernel_launch(void* const* d_in, const int* in_sizes, int n_in,
                              void* d_out, int out_size, void* d_ws, size_t ws_size,
                              hipStream_t stream)
{
    const float* x      = (const float*)d_in[0];
    const float* Wi     = (const float*)d_in[1];
    const float* bi     = (const float*)d_in[2];
    const float* conv_w = (const float*)d_in[3];
    const float* conv_b = (const float*)d_in[4];
    const float* Wp     = (const float*)d_in[5];
    const float* bp     = (const float*)d_in[6];
    const float* Wh     = (const float*)d_in[7];
    const float* bh     = (const float*)d_in[8];
    const float* Wq     = (const float*)d_in[9];
    const float* bq     = (const float*)d_in[10];
    const float* Wk     = (const float*)d_in[11];
    const float* bk     = (const float*)d_in[12];
    const float* Wv     = (const float*)d_in[13];
    const float* bv     = (const float*)d_in[14];
    const float* W1     = (const float*)d_in[15];
    const float* b1     = (const float*)d_in[16];
    const float* W2     = (const float*)d_in[17];
    const float* b2     = (const float*)d_in[18];
    const float* Wo     = (const float*)d_in[19];
    const float* bo     = (const float*)d_in[20];
    float* out = (float*)d_out;

    char* p = (char*)d_ws;
    auto alloc = [&](size_t bytes) { char* r = p; p += (bytes + 255) & ~(size_t)255; return r; };

    u16*  xb     = (u16*)alloc((size_t)BS_ * DM_ * 2);
    u16*  h      = (u16*)alloc((size_t)BS_ * DS_ * 2);
    u16*  mixed  = (u16*)alloc((size_t)BS_ * DS_ * 2);
    u16*  qkv    = (u16*)alloc((size_t)BS_ * 768 * 2);
    u16*  sm     = (u16*)alloc((size_t)BS_ * DS_ * 2);
    u16*  tb     = (u16*)alloc((size_t)BS_ * DS_ * 2);
    u16*  php    = (u16*)alloc((size_t)512 * DS_ * 2);
    float* gate  = (float*)alloc((size_t)BS_ * 4);
    float* scores= (float*)alloc((size_t)BS_ * 64 * 4);
    float* bqkv  = (float*)alloc(768 * 4);
    u16* Wit     = (u16*)alloc((size_t)256 * 1024 * 2);
    u16* Wqkvt   = (u16*)alloc((size_t)768 * 256 * 2);
    u16* Wpt     = (u16*)alloc((size_t)256 * 256 * 2);
    u16* W1t     = (u16*)alloc((size_t)256 * 1024 * 2);
    u16* W2t     = (u16*)alloc((size_t)256 * 256 * 2);
    u16* Wot     = (u16*)alloc((size_t)1024 * 256 * 2);

    dim3 blk(256);

    // ---- prep (cvt x + all weight transposes + bias concat) ----
    prep_all_k<<<5185, blk, 0, stream>>>(x, Wi, Wq, Wk, Wv, Wp, W1, W2, Wo,
                                         bq, bk, bv, xb,
                                         Wit, Wqkvt, Wpt, W1t, W2t, Wot, bqkv);

    // ---- forward ----
    // h = x @ Wi + bi
    mm_k<2, 0><<<512, blk, 0, stream>>>(xb, Wit, bi, h, DM_, DS_, 4, nullptr, nullptr);

    for (int step = 0; step < 2; ++step) {
        // packed: qkv GEMM (768 blocks) + conv/pool/gate/php (512 blocks)
        step_a_k<<<1280, blk, 0, stream>>>(h, Wqkvt, bqkv, qkv,
                                           conv_w, conv_b, Wh, bh, Wpt, bp,
                                           mixed, php, gate);
        scores_k<<<256, blk, 0, stream>>>(qkv, scores);
        select_k<<<2048, blk, 0, stream>>>(scores, qkv, sm);
        mm_ui_k<<<512, blk, 0, stream>>>(h, mixed, php, sm, W1t, b1, tb);
        // h = h + (tanh(ui@W1+b1) @ W2 + b2) * gate
        mm_k<2, 2><<<512, blk, 0, stream>>>(tb, W2t, b2, h, DS_, DS_, 4, h, gate);
    }

    // out = x + h @ Wo + bo
    mm_k<4, 3><<<1024, blk, 0, stream>>>(h, Wot, bo, out, DS_, DM_, 16, xb, nullptr);
}

// Round 9
// 150.872 us; speedup vs baseline: 1.5040x; 1.0343x over previous
//
#include <hip/hip_runtime.h>
#include <math.h>

#define B_    4
#define S_    2048
#define BS_   8192       // B_*S_
#define DM_   1024
#define DS_   256
#define LB_   64
#define TOPK_ 8

typedef unsigned short u16;
typedef __bf16 bf16x8 __attribute__((ext_vector_type(8)));
typedef float  f32x4  __attribute__((ext_vector_type(4)));

static __device__ __forceinline__ u16 f2bf(float f) {
    union { float f; unsigned u; } a; a.f = f;
    unsigned u = a.u;
    unsigned r = u + 0x7FFFu + ((u >> 16) & 1u);   // RNE
    return (u16)(r >> 16);
}
static __device__ __forceinline__ float bf2f(u16 v) {
    union { unsigned u; float f; } a; a.u = ((unsigned)v) << 16; return a.f;
}
static __device__ __forceinline__ unsigned pack2(float a, float b) {
    return (unsigned)f2bf(a) | ((unsigned)f2bf(b) << 16);
}
// 16B-granule swizzle within a 64B row (4 granules) -- scores_k staging
static __device__ __forceinline__ int swz(int row, int cb) {
    return (cb ^ (row & 3) ^ ((row >> 2) & 3)) & 3;
}

// async global->LDS, 16B per lane; LDS dest = uniform base + lane*16
#define GLD16(g, l) __builtin_amdgcn_global_load_lds(                         \
    (const __attribute__((address_space(1))) void*)(g),                       \
    (__attribute__((address_space(3))) void*)(l), 16, 0, 0)

// ---------------------------------------------------------------------------
// MFMA bf16 GEMM body, BK=128, double-buffered (T3 minimum 2-phase):
//   prologue STAGE(buf0); loop { STAGE(next); compute(cur); barrier }
// C = epi(A_bf16[M,K] @ Bt_bf16[N,K]^T + bias). MF=2 -> BM=64. BN=64.
// 4 waves (2x2). Staging via global_load_lds: linear LDS dest, source granule
// pre-swizzled lg^(row&15); fragment reads apply the same involution.
// EPI: 0 -> C bf16 | 2 -> C bf16 = extra0_bf16 + val*extra1[m]
//      3 -> C f32  = extra0_bf16 + val.
// ---------------------------------------------------------------------------
template<int MF, int EPI>
__device__ __forceinline__ void mm_dev(
    unsigned char* smem, int id, int nb, int gx,
    const u16* __restrict__ A, const u16* __restrict__ Bt,
    const float* __restrict__ bias, void* __restrict__ Cv,
    int K, int N,
    const void* __restrict__ extra0v, const float* __restrict__ extra1)
{
    constexpr int BM = MF * 32;
    constexpr int ABY = BM * 256;
    constexpr int BBY = 64 * 256;

    const int per = nb >> 3;
    const int nid = (id & 7) * per + (id >> 3);   // bijective XCD chunking
    const int bx  = nid % gx, by = nid / gx;

    const int tid  = threadIdx.x;
    const int lane = tid & 63, wid = tid >> 6;
    const int wm   = wid >> 1, wn = wid & 1;
    const int bm   = by * BM, bn = bx * 64;
    const int lr   = lane & 15, lc = lane >> 4;
    const int l16  = lane >> 4, lg = lane & 15;

    auto stage = [&](int buf, int k0) {
        unsigned char* sA = smem + buf * (ABY + BBY);
        unsigned char* sB = sA + ABY;
        #pragma unroll
        for (int t = 0; t < BM / 16; ++t) {
            int row = wid * (BM / 4) + t * 4 + l16;
            int gg  = lg ^ (row & 15);
            GLD16(A + (size_t)(bm + row) * K + k0 + gg * 8,
                  sA + (size_t)(wid * (BM / 4) + t * 4) * 256);
        }
        #pragma unroll
        for (int t = 0; t < 4; ++t) {
            int row = wid * 16 + t * 4 + l16;
            int gg  = lg ^ (row & 15);
            GLD16(Bt + (size_t)(bn + row) * K + k0 + gg * 8,
                  sB + (size_t)(wid * 16 + t * 4) * 256);
        }
    };

    f32x4 acc[MF][2] = {};

    stage(0, 0);
    __syncthreads();

    const int nt = K >> 7;
    for (int t = 0; t < nt; ++t) {
        if (t + 1 < nt) stage((t + 1) & 1, (t + 1) << 7);

        unsigned char* sA = smem + (t & 1) * (ABY + BBY);
        unsigned char* sB = sA + ABY;
        #pragma unroll
        for (int kk = 0; kk < 4; ++kk) {
            bf16x8 af[MF], bfr[2];
            #pragma unroll
            for (int i = 0; i < MF; ++i) {
                int m = wm * (MF * 16) + i * 16 + lr;
                af[i] = *reinterpret_cast<const bf16x8*>(
                    sA + m * 256 + (((kk * 4 + lc) ^ (m & 15)) * 16));
            }
            #pragma unroll
            for (int j = 0; j < 2; ++j) {
                int n = wn * 32 + j * 16 + lr;
                bfr[j] = *reinterpret_cast<const bf16x8*>(
                    sB + n * 256 + (((kk * 4 + lc) ^ (n & 15)) * 16));
            }
            #pragma unroll
            for (int i = 0; i < MF; ++i)
                #pragma unroll
                for (int j = 0; j < 2; ++j)
                    acc[i][j] = __builtin_amdgcn_mfma_f32_16x16x32_bf16(
                        af[i], bfr[j], acc[i][j], 0, 0, 0);
        }
        __syncthreads();   // next tile staged + current reads done
    }

    #pragma unroll
    for (int i = 0; i < MF; ++i) {
        #pragma unroll
        for (int j = 0; j < 2; ++j) {
            int col = bn + wn * 32 + j * 16 + lr;
            #pragma unroll
            for (int r = 0; r < 4; ++r) {
                int row = bm + wm * (MF * 16) + i * 16 + lc * 4 + r;
                float val = acc[i][j][r] + bias[col];
                if constexpr (EPI == 2) {
                    const u16* e0 = (const u16*)extra0v;
                    val = bf2f(e0[(size_t)row * N + col]) + val * extra1[row];
                    ((u16*)Cv)[(size_t)row * N + col] = f2bf(val);
                } else if constexpr (EPI == 3) {
                    const u16* e0 = (const u16*)extra0v;
                    ((float*)Cv)[(size_t)row * N + col] = bf2f(e0[(size_t)row * N + col]) + val;
                } else {
                    ((u16*)Cv)[(size_t)row * N + col] = f2bf(val);
                }
            }
        }
    }
}

template<int MF, int EPI>
__global__ __launch_bounds__(256) void mm_k(
    const u16* __restrict__ A, const u16* __restrict__ Bt,
    const float* __restrict__ bias, void* __restrict__ Cv,
    int K, int N, int gx,
    const void* __restrict__ extra0v, const float* __restrict__ extra1)
{
    __shared__ __align__(16) unsigned char smem[2 * (MF * 32 * 256 + 64 * 256)];
    mm_dev<MF, EPI>(smem, blockIdx.x, gridDim.x, gx, A, Bt, bias, Cv, K, N,
                    extra0v, extra1);
}

// ---------------------------------------------------------------------------
// ui-concat MFMA GEMM + tanh, BK=128, double-buffered:
// t = tanh([h|mixed|pb|summ] @ W1 + b1); pb[m,:] = php[m>>4,:]. BM=64.
// ---------------------------------------------------------------------------
__global__ __launch_bounds__(256) void mm_ui_k(
    const u16* __restrict__ h, const u16* __restrict__ mixed,
    const u16* __restrict__ php, const u16* __restrict__ summ,
    const u16* __restrict__ W1t, const float* __restrict__ b1,
    u16* __restrict__ t)
{
    __shared__ __align__(16) unsigned char smem[65536];   // 2 x (16KB A + 16KB B)

    const int nb  = gridDim.x;
    const int per = nb >> 3;
    const int id  = blockIdx.x;
    const int nid = (id & 7) * per + (id >> 3);
    const int bx  = nid & 3, by = nid >> 2;

    const int tid  = threadIdx.x;
    const int lane = tid & 63, wid = tid >> 6;
    const int wm   = wid >> 1, wn = wid & 1;
    const int bm   = by * 64, bn = bx * 64;
    const int lr   = lane & 15, lc = lane >> 4;
    const int l16  = lane >> 4, lg = lane & 15;

    auto stage = [&](int buf, int k0) {
        const int seg = k0 >> 8, kb = k0 & 255;
        const u16* Asrc = (seg == 0) ? h : (seg == 1) ? mixed : (seg == 2) ? php : summ;
        unsigned char* sA = smem + buf * 32768;
        unsigned char* sB = sA + 16384;
        #pragma unroll
        for (int tt = 0; tt < 4; ++tt) {
            int row = wid * 16 + tt * 4 + l16;
            int gg  = lg ^ (row & 15);
            int rs  = bm + row;
            if (seg == 2) rs >>= 4;
            GLD16(Asrc + (size_t)rs * DS_ + kb + gg * 8,
                  sA + (size_t)(wid * 16 + tt * 4) * 256);
        }
        #pragma unroll
        for (int tt = 0; tt < 4; ++tt) {
            int row = wid * 16 + tt * 4 + l16;
            int gg  = lg ^ (row & 15);
            GLD16(W1t + (size_t)(bn + row) * 1024 + k0 + gg * 8,
                  sB + (size_t)(wid * 16 + tt * 4) * 256);
        }
    };

    f32x4 acc[2][2] = {};

    stage(0, 0);
    __syncthreads();

    for (int t8 = 0; t8 < 8; ++t8) {
        if (t8 + 1 < 8) stage((t8 + 1) & 1, (t8 + 1) << 7);

        unsigned char* sA = smem + (t8 & 1) * 32768;
        unsigned char* sB = sA + 16384;
        #pragma unroll
        for (int kk = 0; kk < 4; ++kk) {
            bf16x8 af[2], bfr[2];
            #pragma unroll
            for (int i = 0; i < 2; ++i) {
                int m = wm * 32 + i * 16 + lr;
                af[i] = *reinterpret_cast<const bf16x8*>(
                    sA + m * 256 + (((kk * 4 + lc) ^ (m & 15)) * 16));
            }
            #pragma unroll
            for (int j = 0; j < 2; ++j) {
                int n = wn * 32 + j * 16 + lr;
                bfr[j] = *reinterpret_cast<const bf16x8*>(
                    sB + n * 256 + (((kk * 4 + lc) ^ (n & 15)) * 16));
            }
            #pragma unroll
            for (int i = 0; i < 2; ++i)
                #pragma unroll
                for (int j = 0; j < 2; ++j)
                    acc[i][j] = __builtin_amdgcn_mfma_f32_16x16x32_bf16(
                        af[i], bfr[j], acc[i][j], 0, 0, 0);
        }
        __syncthreads();
    }

    #pragma unroll
    for (int i = 0; i < 2; ++i) {
        #pragma unroll
        for (int j = 0; j < 2; ++j) {
            int col = bn + wn * 32 + j * 16 + lr;
            #pragma unroll
            for (int r = 0; r < 4; ++r) {
                int row = bm + wm * 32 + i * 16 + lc * 4 + r;
                t[(size_t)row * DS_ + col] = f2bf(tanhf(acc[i][j][r] + b1[col]));
            }
        }
    }
}

// ---------------------------------------------------------------------------
// Causal depthwise conv (K=5) + chunk mean + halt gate + fused php projection.
// ---------------------------------------------------------------------------
__device__ __forceinline__ void conv_dev(
    unsigned char* smem, int cid,
    const u16* __restrict__ h, const float* __restrict__ conv_w,
    const float* __restrict__ conv_b, const float* __restrict__ Wh,
    const float* __restrict__ bh, const u16* __restrict__ Wpt,
    const float* __restrict__ bp, u16* __restrict__ mixed,
    u16* __restrict__ php, float* __restrict__ gate)
{
    float* gpart = (float*)smem;            // [16][4]
    float* cm    = (float*)(smem + 256);    // [256]
    const int blk = (cid & 7) * 64 + (cid >> 3);   // XCD swizzle (8 x 64)
    const int d = threadIdx.x;
    const int b = blk >> 7;
    const int s0 = (blk & 127) * 16;
    const u16* hb = h + (size_t)b * S_ * DS_;
    u16* mb = mixed + (size_t)b * S_ * DS_;

    const float w0 = conv_w[0 * DS_ + d], w1 = conv_w[1 * DS_ + d],
                w2 = conv_w[2 * DS_ + d], w3 = conv_w[3 * DS_ + d],
                w4 = conv_w[4 * DS_ + d];
    const float cb = conv_b[d];
    const float whd = Wh[d * 3 + 2];

    float a0 = (s0 >= 4) ? bf2f(hb[(size_t)(s0 - 4) * DS_ + d]) : 0.f;
    float a1 = (s0 >= 3) ? bf2f(hb[(size_t)(s0 - 3) * DS_ + d]) : 0.f;
    float a2 = (s0 >= 2) ? bf2f(hb[(size_t)(s0 - 2) * DS_ + d]) : 0.f;
    float a3 = (s0 >= 1) ? bf2f(hb[(size_t)(s0 - 1) * DS_ + d]) : 0.f;

    float sum = 0.f;
    #pragma unroll
    for (int tt = 0; tt < 16; ++tt) {
        int s = s0 + tt;
        float cur = bf2f(hb[(size_t)s * DS_ + d]);
        mb[(size_t)s * DS_ + d] = f2bf(w0 * a0 + w1 * a1 + w2 * a2 + w3 * a3 + w4 * cur + cb);
        sum += cur;
        float g = cur * whd;
        #pragma unroll
        for (int off = 32; off; off >>= 1) g += __shfl_down(g, off);
        if ((d & 63) == 0) gpart[tt * 4 + (d >> 6)] = g;
        a0 = a1; a1 = a2; a2 = a3; a3 = cur;
    }
    cm[d] = sum * (1.f / 16.f);
    __syncthreads();
    if (d < 16) {
        float gg = gpart[d * 4 + 0] + gpart[d * 4 + 1] + gpart[d * 4 + 2] + gpart[d * 4 + 3];
        gate[(size_t)b * S_ + s0 + d] = 1.f / (1.f + expf(-(gg + bh[2])));
    }
    float accp = bp[d];
    const u16* wr = Wpt + (size_t)d * 256;
    #pragma unroll
    for (int k = 0; k < 256; k += 8) {
        bf16x8 w8 = *reinterpret_cast<const bf16x8*>(wr + k);
        accp += cm[k]     * (float)w8[0] + cm[k + 1] * (float)w8[1]
              + cm[k + 2] * (float)w8[2] + cm[k + 3] * (float)w8[3]
              + cm[k + 4] * (float)w8[4] + cm[k + 5] * (float)w8[5]
              + cm[k + 6] * (float)w8[6] + cm[k + 7] * (float)w8[7];
    }
    php[(size_t)blk * DS_ + d] = f2bf(accp);
}

// ---------------------------------------------------------------------------
// Packed launch: blocks 0..1535 qkv GEMM (MF=2, N=768); 1536..2047 conv+php.
// ---------------------------------------------------------------------------
__global__ __launch_bounds__(256) void step_a_k(
    const u16* __restrict__ h, const u16* __restrict__ Wqkvt,
    const float* __restrict__ bqkv, u16* __restrict__ qkv,
    const float* __restrict__ conv_w, const float* __restrict__ conv_b,
    const float* __restrict__ Wh, const float* __restrict__ bh,
    const u16* __restrict__ Wpt, const float* __restrict__ bp,
    u16* __restrict__ mixed, u16* __restrict__ php, float* __restrict__ gate)
{
    __shared__ __align__(16) unsigned char smem[65536];
    if (blockIdx.x < 1536) {
        mm_dev<2, 0>(smem, blockIdx.x, 1536, 12, h, Wqkvt, bqkv, qkv,
                     DS_, 768, nullptr, nullptr);
    } else {
        conv_dev(smem, blockIdx.x - 1536, h, conv_w, conv_b, Wh, bh,
                 Wpt, bp, mixed, php, gate);
    }
}

// ---------------------------------------------------------------------------
// Banded scores via MFMA: scores[t, l] = (q[t] . k[t-64+l]) * scale, f32 out.
// ---------------------------------------------------------------------------
__global__ __launch_bounds__(256) void scores_k(
    const u16* __restrict__ qkv, float* __restrict__ scores)
{
    __shared__ __align__(16) unsigned char smem[32 * 64 + 96 * 64];
    __shared__ float Sld[32][97];
    unsigned char* smA = smem;            // Q chunk: 32 rows x 32 bf16
    unsigned char* smB = smem + 32 * 64;  // K chunk: 96 rows x 32 bf16

    const int bid = blockIdx.x;                    // 256 blocks
    const int blk = (bid & 7) * 32 + (bid >> 3);   // XCD swizzle (8 x 32)
    const int t0 = blk * 32;
    const int b  = t0 >> 11;
    const int s0 = t0 & (S_ - 1);
    const int tid = threadIdx.x;
    const int lane = tid & 63, wid = tid >> 6;
    const int lr = lane & 15, lc = lane >> 4;
    const int qt  = wid & 1;
    const int ktb = (wid >> 1) * 3;

    const u16* qbase = qkv + (size_t)t0 * 768;
    const u16* kbase = qkv + (size_t)b * S_ * 768 + 256;

    f32x4 acc[3] = {};

    for (int k0 = 0; k0 < 256; k0 += 32) {
        #pragma unroll
        for (int i = 0; i < 2; ++i) {
            int e = tid + i * 256;
            const u16* src;
            unsigned char* dst;
            if (e < 128) {
                int row = e >> 2, cb = e & 3;
                src = qbase + (size_t)row * 768 + k0 + cb * 8;
                dst = smA + row * 64 + swz(row, cb) * 16;
            } else {
                int eb = e - 128;
                int row = eb >> 2, cb = eb & 3;
                int krow = s0 - 64 + row;
                if (krow < 0) krow = 0;
                src = kbase + (size_t)krow * 768 + k0 + cb * 8;
                dst = smB + row * 64 + swz(row, cb) * 16;
            }
            *reinterpret_cast<uint4*>(dst) = *reinterpret_cast<const uint4*>(src);
        }
        __syncthreads();

        bf16x8 af, bfr[3];
        {
            int m = qt * 16 + lr;
            af = *reinterpret_cast<const bf16x8*>(smA + m * 64 + swz(m, lc) * 16);
        }
        #pragma unroll
        for (int j = 0; j < 3; ++j) {
            int n = (ktb + j) * 16 + lr;
            bfr[j] = *reinterpret_cast<const bf16x8*>(smB + n * 64 + swz(n, lc) * 16);
        }
        #pragma unroll
        for (int j = 0; j < 3; ++j)
            acc[j] = __builtin_amdgcn_mfma_f32_16x16x32_bf16(af, bfr[j], acc[j], 0, 0, 0);
        __syncthreads();
    }

    #pragma unroll
    for (int j = 0; j < 3; ++j) {
        int col = (ktb + j) * 16 + lr;
        #pragma unroll
        for (int r = 0; r < 4; ++r) {
            int row = qt * 16 + lc * 4 + r;
            Sld[row][col] = acc[j][r];
        }
    }
    __syncthreads();

    #pragma unroll
    for (int it = 0; it < 8; ++it) {
        int e = tid + it * 256;
        int i = e >> 6, l = e & 63;
        scores[(size_t)(t0 + i) * 64 + l] = Sld[i][i + l] * 0.0625f;
    }
}

// ---------------------------------------------------------------------------
// Top-8 select + softmax + V-sum. scores f32, V bf16 (from qkv), summ bf16.
// ---------------------------------------------------------------------------
__global__ __launch_bounds__(256) void select_k(
    const float* __restrict__ scores, const u16* __restrict__ qkv,
    u16* __restrict__ summ)
{
    const int bid = blockIdx.x;                       // 2048 blocks
    const int sb  = (bid & 7) * 256 + (bid >> 3);     // bijective XCD swizzle
    const int m   = sb * 4 + (threadIdx.x >> 6);
    const int b = m >> 11;
    const int s = m & (S_ - 1);
    const int lane = threadIdx.x & 63;

    float sc = (s - LB_ + lane >= 0) ? scores[(size_t)m * 64 + lane] : -INFINITY;

    float vals[TOPK_]; int idxs[TOPK_];
    #pragma unroll
    for (int t = 0; t < TOPK_; ++t) {
        float mv = sc; int mi = lane;
        #pragma unroll
        for (int off = 32; off; off >>= 1) {
            float ov = __shfl_xor(mv, off);
            int   oi = __shfl_xor(mi, off);
            if (ov > mv || (ov == mv && oi < mi)) { mv = ov; mi = oi; }
        }
        vals[t] = mv; idxs[t] = mi;
        if (lane == mi) sc = -INFINITY;
    }

    const float mref = (vals[0] == -INFINITY) ? 0.f : vals[0];
    float e[TOPK_], ssum = 0.f;
    #pragma unroll
    for (int t = 0; t < TOPK_; ++t) { e[t] = expf(vals[t] - mref); ssum += e[t]; }
    const float inv = 1.f / fmaxf(ssum, 1e-30f);

    float out[4] = {0.f, 0.f, 0.f, 0.f};
    #pragma unroll
    for (int t = 0; t < TOPK_; ++t) {
        float wt = e[t] * inv;
        int tok = s - LB_ + idxs[t];
        tok = min(max(tok, 0), S_ - 1);
        const u16* vr = qkv + ((size_t)(b * S_) + tok) * 768 + 512;
        #pragma unroll
        for (int i = 0; i < 4; ++i) out[i] += wt * bf2f(vr[lane + i * 64]);
    }
    #pragma unroll
    for (int i = 0; i < 4; ++i)
        summ[(size_t)m * DS_ + lane + i * 64] = f2bf(out[i]);
}

// ---------------------------------------------------------------------------
// Merged prep: blocks 0..4095 cvt x->bf16; 4096..5183 weight transposes;
// 5184 qkv bias concat.
// ---------------------------------------------------------------------------
__global__ __launch_bounds__(256) void prep_all_k(
    const float* __restrict__ x,
    const float* __restrict__ Wi, const float* __restrict__ Wq,
    const float* __restrict__ Wk, const float* __restrict__ Wv,
    const float* __restrict__ Wp, const float* __restrict__ W1,
    const float* __restrict__ W2, const float* __restrict__ Wo,
    const float* __restrict__ bq, const float* __restrict__ bk,
    const float* __restrict__ bv,
    u16* __restrict__ xb,
    u16* __restrict__ Wit, u16* __restrict__ Wqkvt, u16* __restrict__ Wpt,
    u16* __restrict__ W1t, u16* __restrict__ W2t, u16* __restrict__ Wot,
    float* __restrict__ bqkv)
{
    const int bid0 = blockIdx.x;
    if (bid0 < 4096) {
        int i = (bid0 * 256 + threadIdx.x) * 8;
        float4 a = *reinterpret_cast<const float4*>(x + i);
        float4 b = *reinterpret_cast<const float4*>(x + i + 4);
        uint4 g;
        g.x = pack2(a.x, a.y); g.y = pack2(a.z, a.w);
        g.z = pack2(b.x, b.y); g.w = pack2(b.z, b.w);
        *reinterpret_cast<uint4*>(xb + i) = g;
        return;
    }
    const int bid = bid0 - 4096;
    if (bid >= 1088) {
        for (int i = threadIdx.x; i < 768; i += 256) {
            float v = (i < 256) ? bq[i] : (i < 512) ? bk[i - 256] : bv[i - 512];
            bqkv[i] = v;
        }
        return;
    }
    const float* in; u16* out; int K, N, t;
    if (bid < 256)      { in = Wi; out = Wit;             K = 1024; N = 256;  t = bid; }
    else if (bid < 320) { in = Wq; out = Wqkvt;           K = 256;  N = 256;  t = bid - 256; }
    else if (bid < 384) { in = Wk; out = Wqkvt + 256*256; K = 256;  N = 256;  t = bid - 320; }
    else if (bid < 448) { in = Wv; out = Wqkvt + 512*256; K = 256;  N = 256;  t = bid - 384; }
    else if (bid < 512) { in = Wp; out = Wpt;             K = 256;  N = 256;  t = bid - 448; }
    else if (bid < 768) { in = W1; out = W1t;             K = 1024; N = 256;  t = bid - 512; }
    else if (bid < 832) { in = W2; out = W2t;             K = 256;  N = 256;  t = bid - 768; }
    else                { in = Wo; out = Wot;             K = 256;  N = 1024; t = bid - 832; }
    const int tilesX = N >> 5;
    const int n0 = (t % tilesX) * 32, k0 = (t / tilesX) * 32;
    __shared__ float tl[32][33];
    const int cx = threadIdx.x & 31, cy = threadIdx.x >> 5;
    #pragma unroll
    for (int r = 0; r < 32; r += 8)
        tl[cy + r][cx] = in[(size_t)(k0 + cy + r) * N + n0 + cx];
    __syncthreads();
    #pragma unroll
    for (int r = 0; r < 32; r += 8)
        out[(size_t)(n0 + cy + r) * K + k0 + cx] = f2bf(tl[cx][cy + r]);
}

// ---------------------------------------------------------------------------
extern "C" void kernel_launch(void* const* d_in, const int* in_sizes, int n_in,
                              void* d_out, int out_size, void* d_ws, size_t ws_size,
                              hipStream_t stream)
{
    const float* x      = (const float*)d_in[0];
    const float* Wi     = (const float*)d_in[1];
    const float* bi     = (const float*)d_in[2];
    const float* conv_w = (const float*)d_in[3];
    const float* conv_b = (const float*)d_in[4];
    const float* Wp     = (const float*)d_in[5];
    const float* bp     = (const float*)d_in[6];
    const float* Wh     = (const float*)d_in[7];
    const float* bh     = (const float*)d_in[8];
    const float* Wq     = (const float*)d_in[9];
    const float* bq     = (const float*)d_in[10];
    const float* Wk     = (const float*)d_in[11];
    const float* bk     = (const float*)d_in[12];
    const float* Wv     = (const float*)d_in[13];
    const float* bv     = (const float*)d_in[14];
    const float* W1     = (const float*)d_in[15];
    const float* b1     = (const float*)d_in[16];
    const float* W2     = (const float*)d_in[17];
    const float* b2     = (const float*)d_in[18];
    const float* Wo     = (const float*)d_in[19];
    const float* bo     = (const float*)d_in[20];
    float* out = (float*)d_out;

    char* p = (char*)d_ws;
    auto alloc = [&](size_t bytes) { char* r = p; p += (bytes + 255) & ~(size_t)255; return r; };

    u16*  xb     = (u16*)alloc((size_t)BS_ * DM_ * 2);
    u16*  h      = (u16*)alloc((size_t)BS_ * DS_ * 2);
    u16*  mixed  = (u16*)alloc((size_t)BS_ * DS_ * 2);
    u16*  qkv    = (u16*)alloc((size_t)BS_ * 768 * 2);
    u16*  sm     = (u16*)alloc((size_t)BS_ * DS_ * 2);
    u16*  tb     = (u16*)alloc((size_t)BS_ * DS_ * 2);
    u16*  php    = (u16*)alloc((size_t)512 * DS_ * 2);
    float* gate  = (float*)alloc((size_t)BS_ * 4);
    float* scores= (float*)alloc((size_t)BS_ * 64 * 4);
    float* bqkv  = (float*)alloc(768 * 4);
    u16* Wit     = (u16*)alloc((size_t)256 * 1024 * 2);
    u16* Wqkvt   = (u16*)alloc((size_t)768 * 256 * 2);
    u16* Wpt     = (u16*)alloc((size_t)256 * 256 * 2);
    u16* W1t     = (u16*)alloc((size_t)256 * 1024 * 2);
    u16* W2t     = (u16*)alloc((size_t)256 * 256 * 2);
    u16* Wot     = (u16*)alloc((size_t)1024 * 256 * 2);

    dim3 blk(256);

    // ---- prep (cvt x + all weight transposes + bias concat) ----
    prep_all_k<<<5185, blk, 0, stream>>>(x, Wi, Wq, Wk, Wv, Wp, W1, W2, Wo,
                                         bq, bk, bv, xb,
                                         Wit, Wqkvt, Wpt, W1t, W2t, Wot, bqkv);

    // ---- forward ----
    // h = x @ Wi + bi
    mm_k<2, 0><<<512, blk, 0, stream>>>(xb, Wit, bi, h, DM_, DS_, 4, nullptr, nullptr);

    for (int step = 0; step < 2; ++step) {
        // packed: qkv GEMM (1536 blocks, MF=2) + conv/pool/gate/php (512)
        step_a_k<<<2048, blk, 0, stream>>>(h, Wqkvt, bqkv, qkv,
                                           conv_w, conv_b, Wh, bh, Wpt, bp,
                                           mixed, php, gate);
        scores_k<<<256, blk, 0, stream>>>(qkv, scores);
        select_k<<<2048, blk, 0, stream>>>(scores, qkv, sm);
        mm_ui_k<<<512, blk, 0, stream>>>(h, mixed, php, sm, W1t, b1, tb);
        // h = h + (tanh(ui@W1+b1) @ W2 + b2) * gate
        mm_k<2, 2><<<512, blk, 0, stream>>>(tb, W2t, b2, h, DS_, DS_, 4, h, gate);
    }

    // out = x + h @ Wo + bo
    mm_k<2, 3><<<2048, blk, 0, stream>>>(h, Wot, bo, out, DS_, DM_, 16, xb, nullptr);
}